// Round 5
// baseline (669.321 us; speedup 1.0000x reference)
//
#include <hip/hip_runtime.h>
#include <hip/hip_bf16.h>

// SpecAttn: out = softmax((x@Wq+bq)(x@Wk+bk)^T / 32) @ (x@Wv+bv) @ Wo + bo
// B=8, S=2048, H=1024. bf16 MFMA everywhere, fp32 accumulate.
// R10: R9 + pipelined fragment reads. R9's phase put ds_reads between two
//     barriers -> LDS-read region and MFMA region strictly serialized per CU
//     (measured 33% MfmaUtil = MFMA 1242cy + reads ~1500cy + 16 barriers).
//     R10 phase p: [stages] [pre-read regs for phase p+1] lgkmcnt(counted:
//     just-issued may fly, forces last phase's regs) -> MFMA_p -> ONE barrier.
//     Reads overlap MFMA on the other pipe; 8 barriers/iter (was 16).
//     Ledger: stages B(t+2)@P0,P1  A(t+2)@P3,P4  B(t+3)@P5,P6  A(t+3)@P7;
//     WV(4) at P2-end (forces buf1 = B(t+1),A(t+1) for P3's 12-read batch)
//     and P6-end (forces buf0' = B(t+2),A(t+2) for P7's batch). vmcnt never
//     0 in main loop. Double A-frag sets (sA/tA) + per-tile B sets (bfX/bfY),
//     all static names. sched_barrier(0) after every waitcnt/barrier.

typedef __attribute__((ext_vector_type(8))) __bf16 bf16x8;
typedef __attribute__((ext_vector_type(4))) __bf16 bf16x4;
typedef __attribute__((ext_vector_type(4))) float  f32x4;
typedef __attribute__((ext_vector_type(8))) float  f32x8;

__device__ __forceinline__ void gl_lds16(const void* g, void* l) {
    __builtin_amdgcn_global_load_lds(
        (__attribute__((address_space(1))) const void*)g,
        (__attribute__((address_space(3))) void*)l, 16, 0, 0);
}

template <bool SWP>
__device__ __forceinline__ f32x4 mfma16(bf16x8 a, bf16x8 b, f32x4 c) {
    if constexpr (SWP)
        return __builtin_amdgcn_mfma_f32_16x16x32_bf16(b, a, c, 0, 0, 0);
    else
        return __builtin_amdgcn_mfma_f32_16x16x32_bf16(a, b, c, 0, 0, 0);
}

// ---------------- fp32 -> bf16 convert (x) ----------------
__global__ __launch_bounds__(256) void k_convert(const float* __restrict__ in,
                                                 __bf16* __restrict__ out) {
    const int i = blockIdx.x * 256 + threadIdx.x;   // 8 elems/thread, exact fit
    f32x8 a = *((const f32x8*)in + i);
    bf16x8 o;
#pragma unroll
    for (int j = 0; j < 8; ++j) o[j] = (__bf16)a[j];
    *((bf16x8*)out + i) = o;
}

// --- fp32 W[k][n] -> bf16 Wt[n][k] (1024x1024), z selects weight ---
__global__ __launch_bounds__(256) void k_transpose_w(
    const float* __restrict__ w0, const float* __restrict__ w1,
    const float* __restrict__ w2, const float* __restrict__ w3,
    __bf16* __restrict__ Wt) {
    const int z = blockIdx.z;
    const float* W = (z == 0) ? w0 : (z == 1) ? w1 : (z == 2) ? w2 : w3;
    __bf16* Wo = Wt + (long long)z * 1048576;
    __shared__ float t[64][65];
    const int tid = threadIdx.x;
    const int c4 = (tid & 15) * 4, r0 = tid >> 4;
    const int bx = blockIdx.x * 64, by = blockIdx.y * 64;
#pragma unroll
    for (int p = 0; p < 4; ++p) {
        const int r = r0 + p * 16;
        f32x4 v = *(const f32x4*)(W + (long long)(by + r) * 1024 + bx + c4);
#pragma unroll
        for (int j = 0; j < 4; ++j) t[r][c4 + j] = v[j];
    }
    __syncthreads();
#pragma unroll
    for (int p = 0; p < 4; ++p) {
        const int r = r0 + p * 16;
        bf16x4 o;
#pragma unroll
        for (int j = 0; j < 4; ++j) o[j] = (__bf16)t[c4 + j][r];
        *(bf16x4*)(Wo + (long long)(bx + r) * 1024 + by + c4) = o;
    }
}

// ------------- concat biases into bcat[3072] fp32 -------------
__global__ __launch_bounds__(256) void k_bcat(const float* __restrict__ bq,
                                              const float* __restrict__ bk,
                                              const float* __restrict__ bv,
                                              float* __restrict__ bc) {
    const int i = blockIdx.x * 256 + threadIdx.x;  // grid 12 -> 3072
    const float* s = (i < 1024) ? bq : (i < 2048 ? bk : bv);
    bc[i] = s[i & 1023];
}

// ------------- row softmax over 2048 cols, in place, bf16 -------------
__global__ __launch_bounds__(256) void k_softmax(__bf16* __restrict__ E) {
    __bf16* p = E + (long long)blockIdx.x * 2048;
    const int tid = threadIdx.x, l = tid & 63, w = tid >> 6;
    bf16x8 vb = *((const bf16x8*)p + tid);
    float v[8];
#pragma unroll
    for (int i = 0; i < 8; ++i) v[i] = (float)vb[i];
    float m = v[0];
#pragma unroll
    for (int i = 1; i < 8; ++i) m = fmaxf(m, v[i]);
    for (int off = 32; off > 0; off >>= 1) m = fmaxf(m, __shfl_xor(m, off));
    __shared__ float redm[4], reds[4];
    if (l == 0) redm[w] = m;
    __syncthreads();
    m = fmaxf(fmaxf(redm[0], redm[1]), fmaxf(redm[2], redm[3]));
    float e[8], s = 0.f;
#pragma unroll
    for (int i = 0; i < 8; ++i) { e[i] = __expf(v[i] - m); s += e[i]; }
    for (int off = 32; off > 0; off >>= 1) s += __shfl_xor(s, off);
    if (l == 0) reds[w] = s;
    __syncthreads();
    s = reds[0] + reds[1] + reds[2] + reds[3];
    const float inv = 1.0f / s;
    bf16x8 o;
#pragma unroll
    for (int i = 0; i < 8; ++i) o[i] = (__bf16)(e[i] * inv);
    *((bf16x8*)p + tid) = o;
}

// ------------- GEMM: C[z] = A[z] @ Bt[z]^T * scale (+bias) -------------
// 256x256 tile, BK=64, 8 waves (2x4), wave tile 128x64, pipelined 8-phase.
// LDS [row 256][64], chunk swizzle c' = c ^ (row&7) (c in 0..7 of 16B).
// MODE: 0 = bf16 C swapped, 1 = f32 C swapped, 2 = Q/K split swapped,
//       4 = V unswapped (cols -> Vt[b][h][s]).
template <int MODE, bool HAS_BIAS>
__global__ __launch_bounds__(512, 2) void gemm_bt(
    const __bf16* __restrict__ A, const __bf16* __restrict__ Bt,
    const float* __restrict__ bias, void* __restrict__ Cout,
    int K, int lda, int ldb, int ldc, int gy, int rpx, int bnc,
    float scale, long long sA, long long sB, long long sC) {
    constexpr bool SWP = (MODE != 4);
    __shared__ __align__(16) __bf16 Abuf0[16384];
    __shared__ __align__(16) __bf16 Bbuf0[16384];
    __shared__ __align__(16) __bf16 Abuf1[16384];
    __shared__ __align__(16) __bf16 Bbuf1[16384];

    // swizzled block mapping
    const int lid = blockIdx.x;
    const int xcd = lid & 7;
    const int jj = lid >> 3;
    const int bn = jj % bnc;
    const int rt = xcd * rpx + jj / bnc;
    const int z = rt / gy;
    const int bm = rt - z * gy;

    const __bf16* Ab = A + (long long)z * sA;
    const __bf16* Bb = Bt + (long long)z * sB;

    const int tid = threadIdx.x;
    const int l = tid & 63, w = tid >> 6;   // lane, wave 0..7
    const int wm = w >> 2, wn = w & 3;      // 2 x 4 wave grid

    // staging: thread t covers rows (t>>3)+64j, global chunk (t&7)^((t>>3)&7)
    const int rA = tid >> 3;
    const int cswz = (tid & 7) ^ (rA & 7);
    const __bf16* aSg = Ab + (long long)(bm * 256 + rA) * lda + cswz * 8;
    const __bf16* bSg = Bb + (long long)(bn * 256 + rA) * ldb + cswz * 8;
    const long long a64 = (long long)lda * 64;
    const long long b64 = (long long)ldb * 64;
    const int ldst = tid * 16;              // LDS byte base (linear)

    // ds-read fragment offsets (elements): row stride 64.
    // chunk for (kq4,kh): (kh*4+kq4) ^ (r16&7); kh=1 base = kh=0 base ^ 32.
    const int r16 = l & 15, kq4 = l >> 4;
    const int sw0 = kq4 ^ (r16 & 7);
    const int aro0 = (wm * 128 + r16) * 64 + sw0 * 8;
    const int aro1 = aro0 ^ 32;
    const int bro0 = (wn * 64 + r16) * 64 + sw0 * 8;
    const int bro1 = bro0 ^ 32;

    f32x4 acc[8][4] = {};
    bf16x8 bfX[4][2], bfY[4][2];
    bf16x8 sAk00, sAk01, sAk10, sAk11;   // A-frag set S
    bf16x8 tAk00, tAk01, tAk10, tAk11;   // A-frag set T

#define ST_A(buf, j, t)                                                    \
    gl_lds16(aSg + (j) * a64 + (long long)(t) * 64,                        \
             (char*)(buf) + ldst + (j) * 8192)
#define ST_B(buf, j, t)                                                    \
    gl_lds16(bSg + (j) * b64 + (long long)(t) * 64,                        \
             (char*)(buf) + ldst + (j) * 8192)

// pre-read A-frag set (mi-pair 2*np, 2*np+1) of buffer into named set N
#define PRA(N, buf, np)                                                    \
    do {                                                                   \
        N##k00 = *(const bf16x8*)((buf) + aro0 + (2 * (np)) * 1024);       \
        N##k01 = *(const bf16x8*)((buf) + aro1 + (2 * (np)) * 1024);       \
        N##k10 = *(const bf16x8*)((buf) + aro0 + (2 * (np) + 1) * 1024);   \
        N##k11 = *(const bf16x8*)((buf) + aro1 + (2 * (np) + 1) * 1024);   \
    } while (0)

// pre-read full B tile of buffer into BN[4][2]
#define PRB(BN, buf)                                                       \
    do {                                                                   \
        _Pragma("unroll") for (int ni = 0; ni < 4; ++ni) {                 \
            BN[ni][0] = *(const bf16x8*)((buf) + bro0 + ni * 1024);        \
            BN[ni][1] = *(const bf16x8*)((buf) + bro1 + ni * 1024);        \
        }                                                                  \
    } while (0)

// 16 MFMA for sub-phase pp using A-set U and B-set BC (kh0 x8 then kh1 x8)
#define MM16(pp, U, BC)                                                       \
    do {                                                                      \
        __builtin_amdgcn_s_setprio(1);                                        \
        _Pragma("unroll") for (int ni = 0; ni < 4; ++ni) {                    \
            acc[2*(pp)][ni]   = mfma16<SWP>(U##k00, BC[ni][0], acc[2*(pp)][ni]);   \
            acc[2*(pp)+1][ni] = mfma16<SWP>(U##k10, BC[ni][0], acc[2*(pp)+1][ni]); \
        }                                                                     \
        _Pragma("unroll") for (int ni = 0; ni < 4; ++ni) {                    \
            acc[2*(pp)][ni]   = mfma16<SWP>(U##k01, BC[ni][1], acc[2*(pp)][ni]);   \
            acc[2*(pp)+1][ni] = mfma16<SWP>(U##k11, BC[ni][1], acc[2*(pp)+1][ni]); \
        }                                                                     \
        __builtin_amdgcn_s_setprio(0);                                        \
    } while (0)

#define LGK(n)                                                             \
    do {                                                                   \
        asm volatile("s_waitcnt lgkmcnt(" #n ")" ::: "memory");            \
        __builtin_amdgcn_sched_barrier(0);                                 \
    } while (0)
#define WVC(n) asm volatile("s_waitcnt vmcnt(" #n ")" ::: "memory")
#define BARR                                                               \
    do {                                                                   \
        __builtin_amdgcn_s_barrier();                                      \
        __builtin_amdgcn_sched_barrier(0);                                 \
    } while (0)

    // Prologue: stage both buffers (tiles 0,1); force tile 0; pre-read P0 regs.
    ST_B(Bbuf0, 0, 0); ST_B(Bbuf0, 1, 0); ST_B(Bbuf0, 2, 0); ST_B(Bbuf0, 3, 0);
    ST_A(Abuf0, 0, 0); ST_A(Abuf0, 1, 0); ST_A(Abuf0, 2, 0); ST_A(Abuf0, 3, 0);
    ST_B(Bbuf1, 0, 1); ST_B(Bbuf1, 1, 1); ST_B(Bbuf1, 2, 1); ST_B(Bbuf1, 3, 1);
    ST_A(Abuf1, 0, 1); ST_A(Abuf1, 1, 1); ST_A(Abuf1, 2, 1); ST_A(Abuf1, 3, 1);
    WVC(8);
    BARR;
    PRB(bfX, Bbuf0);
    PRA(sA, Abuf0, 0);

    const int NT = K >> 6;  // K-tiles of 64; NT even, >= 4 for all dispatches
    for (int t0 = 0; t0 + 3 < NT; t0 += 2) {
        // P0: MFMA sub0(buf0); pre A1; stage B(t0+2) 0,1
        ST_B(Bbuf0, 0, t0 + 2); ST_B(Bbuf0, 1, t0 + 2);
        PRA(tA, Abuf0, 1);
        LGK(4); MM16(0, sA, bfX); BARR;
        // P1: pre A2; stage B(t0+2) 2,3
        ST_B(Bbuf0, 2, t0 + 2); ST_B(Bbuf0, 3, t0 + 2);
        PRA(sA, Abuf0, 2);
        LGK(4); MM16(1, tA, bfX); BARR;
        // P2: pre A3; WV4 (forces buf1 = B(t0+1),A(t0+1))
        PRA(tA, Abuf0, 3);
        LGK(4); MM16(2, sA, bfX); WVC(4); BARR;
        // P3: pre buf1 B + A0; stage A(t0+2) 0,1
        ST_A(Abuf0, 0, t0 + 2); ST_A(Abuf0, 1, t0 + 2);
        PRB(bfY, Bbuf1); PRA(sA, Abuf1, 0);
        LGK(12); MM16(3, tA, bfX); BARR;
        // P4: pre A1(buf1); stage A(t0+2) 2,3
        ST_A(Abuf0, 2, t0 + 2); ST_A(Abuf0, 3, t0 + 2);
        PRA(tA, Abuf1, 1);
        LGK(4); MM16(0, sA, bfY); BARR;
        // P5: pre A2; stage B(t0+3) 0,1
        ST_B(Bbuf1, 0, t0 + 3); ST_B(Bbuf1, 1, t0 + 3);
        PRA(sA, Abuf1, 2);
        LGK(4); MM16(1, tA, bfY); BARR;
        // P6: pre A3; stage B(t0+3) 2,3; WV4 (forces buf0' = B,A(t0+2))
        ST_B(Bbuf1, 2, t0 + 3); ST_B(Bbuf1, 3, t0 + 3);
        PRA(tA, Abuf1, 3);
        LGK(4); MM16(2, sA, bfY); WVC(4); BARR;
        // P7: pre buf0' B + A0; stage A(t0+3) all
        ST_A(Abuf1, 0, t0 + 3); ST_A(Abuf1, 1, t0 + 3);
        ST_A(Abuf1, 2, t0 + 3); ST_A(Abuf1, 3, t0 + 3);
        PRB(bfX, Bbuf0); PRA(sA, Abuf0, 0);
        LGK(12); MM16(3, tA, bfY); BARR;
    }
    // Tail iteration (tiles NT-2, NT-1): no stages; drain vmcnt at P2.
    PRA(tA, Abuf0, 1); LGK(4);  MM16(0, sA, bfX); BARR;
    PRA(sA, Abuf0, 2); LGK(4);  MM16(1, tA, bfX); BARR;
    PRA(tA, Abuf0, 3); LGK(4);  MM16(2, sA, bfX); WVC(0); BARR;
    PRB(bfY, Bbuf1); PRA(sA, Abuf1, 0);
    LGK(12); MM16(3, tA, bfX); BARR;
    PRA(tA, Abuf1, 1); LGK(4);  MM16(0, sA, bfY); BARR;
    PRA(sA, Abuf1, 2); LGK(4);  MM16(1, tA, bfY); BARR;
    PRA(tA, Abuf1, 3); LGK(4);  MM16(2, sA, bfY); BARR;
    LGK(0); MM16(3, tA, bfY);
#undef ST_A
#undef ST_B
#undef PRA
#undef PRB
#undef MM16
#undef LGK
#undef WVC
#undef BARR

    const int quad = kq4;
    if constexpr (MODE == 2) {
        // swapped: row(s) = ...+r16, cols = ...+quad*4+rr -> bf16x4 stores
        __bf16* Qb = (__bf16*)Cout;
        const int part = bn >> 2;  // 0=Q 1=K
#pragma unroll
        for (int mi = 0; mi < 8; ++mi) {
            const int srow0 = bm * 256 + wm * 128 + mi * 16 + r16;
            const int b = srow0 >> 11;
            const int s0 = srow0 & 2047;
#pragma unroll
            for (int ni = 0; ni < 4; ++ni) {
                const int col0 = bn * 256 + wn * 64 + ni * 16 + quad * 4;
                const f32x4 bb = *(const f32x4*)(bias + col0);
                const int c1 = col0 - part * 1024;
                bf16x4 o;
#pragma unroll
                for (int rr = 0; rr < 4; ++rr) o[rr] = (__bf16)(acc[mi][ni][rr] + bb[rr]);
                *(bf16x4*)(Qb + (long long)part * 16777216 +
                           (long long)b * 2097152 + (long long)s0 * 1024 + c1) = o;
            }
        }
    } else if constexpr (MODE == 4) {
        // unswapped: col(h) = ...+r16, rows(s) = ...+quad*4+rr -> bf16x4 along s
        __bf16* Vb = (__bf16*)Cout;
#pragma unroll
        for (int mi = 0; mi < 8; ++mi) {
            const int srow0 = bm * 256 + wm * 128 + mi * 16 + quad * 4;
            const int b = srow0 >> 11;
            const int s0 = srow0 & 2047;
#pragma unroll
            for (int ni = 0; ni < 4; ++ni) {
                const int c1 = bn * 256 + wn * 64 + ni * 16 + r16;
                const float bb = HAS_BIAS ? bias[c1] : 0.0f;
                bf16x4 o;
#pragma unroll
                for (int rr = 0; rr < 4; ++rr) o[rr] = (__bf16)(acc[mi][ni][rr] + bb);
                *(bf16x4*)(Vb + (long long)b * 2097152 +
                           (long long)c1 * 2048 + s0) = o;
            }
        }
    } else {
        // MODE 0/1 swapped row-major: vector store of 4 consecutive cols
        const long long cbase = (long long)z * sC;
#pragma unroll
        for (int mi = 0; mi < 8; ++mi) {
            const int row = bm * 256 + wm * 128 + mi * 16 + r16;
#pragma unroll
            for (int ni = 0; ni < 4; ++ni) {
                const int col0 = bn * 256 + wn * 64 + ni * 16 + quad * 4;
                f32x4 v;
                if constexpr (HAS_BIAS) {
                    const f32x4 bb = *(const f32x4*)(bias + col0);
#pragma unroll
                    for (int rr = 0; rr < 4; ++rr) v[rr] = acc[mi][ni][rr] * scale + bb[rr];
                } else {
#pragma unroll
                    for (int rr = 0; rr < 4; ++rr) v[rr] = acc[mi][ni][rr] * scale;
                }
                if constexpr (MODE == 1) {
                    *(f32x4*)((float*)Cout + cbase + (long long)row * ldc + col0) = v;
                } else {
                    bf16x4 o;
#pragma unroll
                    for (int rr = 0; rr < 4; ++rr) o[rr] = (__bf16)v[rr];
                    *(bf16x4*)((__bf16*)Cout + cbase + (long long)row * ldc + col0) = o;
                }
            }
        }
    }
}

extern "C" void kernel_launch(void* const* d_in, const int* in_sizes, int n_in,
                              void* d_out, int out_size, void* d_ws, size_t ws_size,
                              hipStream_t stream) {
    const float* x  = (const float*)d_in[0];
    const float* wq = (const float*)d_in[1];
    const float* bq = (const float*)d_in[2];
    const float* wk = (const float*)d_in[3];
    const float* bk = (const float*)d_in[4];
    const float* wv = (const float*)d_in[5];
    const float* bv = (const float*)d_in[6];
    const float* wo = (const float*)d_in[7];
    const float* bo = (const float*)d_in[8];
    float* out = (float*)d_out;

    // ws layout (bf16 elems), ~200 MiB total.
    __bf16* ws  = (__bf16*)d_ws;
    __bf16* Xb  = ws;                   // 16,777,216 (phase 1; dead after QKV)
    __bf16* E   = ws;                   // 33,554,432 (phase 2, reuses Xb)
    __bf16* Q   = ws + 33554432;        // 16,777,216
    __bf16* Kb  = ws + 50331648;        // 16,777,216
    __bf16* Vt  = ws + 67108864;        // 16,777,216
    __bf16* Ctx = ws + 83886080;        // 16,777,216
    __bf16* WT  = ws + 100663296;       // 4,194,304
    float*  bc  = (float*)(ws + 104857600);  // 3072 fp32

    k_convert<<<8192, 256, 0, stream>>>(x, Xb);
    k_transpose_w<<<dim3(16, 16, 4), 256, 0, stream>>>(wq, wk, wv, wo, WT);
    k_bcat<<<12, 256, 0, stream>>>(bq, bk, bv, bc);

    // Q,K: [16384,2048] = Xb @ WT[0:2048]^T + bcat -> Q, K (split epilogue)
    gemm_bt<2, true><<<512, 512, 0, stream>>>(
        Xb, WT, bc, Q, 1024, 1024, 1024, 0, 64, 8, 8, 1.0f, 0, 0, 0);

    // V: [16384,1024] = Xb @ WT[2048:3072]^T + bcat[2048:] -> Vt[b][h][s]
    gemm_bt<4, true><<<256, 512, 0, stream>>>(
        Xb, WT + 2097152, bc + 2048, Vt, 1024, 1024, 1024, 0, 64, 8, 4,
        1.0f, 0, 0, 0);

    // E[b] = Q[b] @ K[b]^T / 32
    gemm_bt<0, false><<<512, 512, 0, stream>>>(
        Q, Kb, nullptr, E, 1024, 1024, 1024, 2048, 8, 8, 8,
        0.03125f, 2097152, 2097152, 4194304);

    k_softmax<<<16384, 256, 0, stream>>>(E);

    // Ctx[b] = P[b] @ Vt[b]^T
    gemm_bt<0, false><<<256, 512, 0, stream>>>(
        E, Vt, nullptr, Ctx, 2048, 2048, 2048, 1024, 8, 8, 4,
        1.0f, 4194304, 2097152, 2097152);

    // out = Ctx @ Wo^T + bo (fp32)
    gemm_bt<1, true><<<256, 512, 0, stream>>>(
        Ctx, WT + 3145728, bo, out, 1024, 1024, 1024, 1024, 64, 8, 4,
        1.0f, 0, 0, 0);
}

// Round 6
// 431.219 us; speedup vs baseline: 1.5522x; 1.5522x over previous
//
#include <hip/hip_runtime.h>
#include <hip/hip_bf16.h>

// SpecAttn: out = softmax((x@Wq+bq)(x@Wk+bk)^T / 32) @ (x@Wv+bv) @ Wo + bo
// B=8, S=2048, H=1024. bf16 MFMA everywhere, fp32 accumulate.
// R11: R9 register footprint (no reg-level pipelining: R10 spilled ~50
//     regs/thread -> 130GB scratch traffic) + RELAXED BARRIER LEDGER:
//     one s_barrier per phase (reads+stages issue pre-barrier, lgkmcnt(0)
//     + MFMA post-barrier), extra barrier only after P3/P7 (fused with
//     WV4). Stage targets re-timed so every stage hits a buffer whose
//     reads ended >=2 phases earlier (B(t+2) at P2/P3, A(t+2) at P4/P5,
//     B(t+3) at P6/P7, A(t+1) at P0). Barriers 16->10/iter; waves no
//     longer MFMA-lockstep, so cross-wave ds_read/MFMA overlap happens at
//     zero register cost. vmcnt ledger: entry 4 in flight; WV4@P3 forces
//     {B,A}(t+1); WV4@P7 forces {B,A}(t+2); drain only in tail.
//     Glue: convert+transpose+bcat merged into k_prep; softmax 2 rows/blk.

typedef __attribute__((ext_vector_type(8))) __bf16 bf16x8;
typedef __attribute__((ext_vector_type(4))) __bf16 bf16x4;
typedef __attribute__((ext_vector_type(4))) float  f32x4;
typedef __attribute__((ext_vector_type(8))) float  f32x8;

__device__ __forceinline__ void gl_lds16(const void* g, void* l) {
    __builtin_amdgcn_global_load_lds(
        (__attribute__((address_space(1))) const void*)g,
        (__attribute__((address_space(3))) void*)l, 16, 0, 0);
}

template <bool SWP>
__device__ __forceinline__ f32x4 mfma16(bf16x8 a, bf16x8 b, f32x4 c) {
    if constexpr (SWP)
        return __builtin_amdgcn_mfma_f32_16x16x32_bf16(b, a, c, 0, 0, 0);
    else
        return __builtin_amdgcn_mfma_f32_16x16x32_bf16(a, b, c, 0, 0, 0);
}

// -------- prep: fp32->bf16 convert (x) | W transposes | bias concat --------
__global__ __launch_bounds__(256) void k_prep(
    const float* __restrict__ x,
    const float* __restrict__ w0, const float* __restrict__ w1,
    const float* __restrict__ w2, const float* __restrict__ w3,
    const float* __restrict__ bq, const float* __restrict__ bk,
    const float* __restrict__ bv,
    __bf16* __restrict__ Xb, __bf16* __restrict__ WT, float* __restrict__ bc) {
    __shared__ float tsh[64][65];
    const int bid = blockIdx.x, tid = threadIdx.x;
    if (bid < 8192) {
        const int i = bid * 256 + tid;   // 8 elems/thread, exact fit
        f32x8 a = *((const f32x8*)x + i);
        bf16x8 o;
#pragma unroll
        for (int j = 0; j < 8; ++j) o[j] = (__bf16)a[j];
        *((bf16x8*)Xb + i) = o;
    } else if (bid < 9216) {
        const int tt = bid - 8192;       // 1024 transpose blocks
        const int z = tt >> 8, rem = tt & 255;
        const int bx = (rem & 15) * 64, by = (rem >> 4) * 64;
        const float* W = (z == 0) ? w0 : (z == 1) ? w1 : (z == 2) ? w2 : w3;
        __bf16* Wo = WT + (long long)z * 1048576;
        const int c4 = (tid & 15) * 4, r0 = tid >> 4;
#pragma unroll
        for (int p = 0; p < 4; ++p) {
            const int r = r0 + p * 16;
            f32x4 v = *(const f32x4*)(W + (long long)(by + r) * 1024 + bx + c4);
#pragma unroll
            for (int j = 0; j < 4; ++j) tsh[r][c4 + j] = v[j];
        }
        __syncthreads();
#pragma unroll
        for (int p = 0; p < 4; ++p) {
            const int r = r0 + p * 16;
            bf16x4 o;
#pragma unroll
            for (int j = 0; j < 4; ++j) o[j] = (__bf16)tsh[c4 + j][r];
            *(bf16x4*)(Wo + (long long)(bx + r) * 1024 + by + c4) = o;
        }
    } else {
        const int i = (bid - 9216) * 256 + tid;  // 12 blocks -> 3072
        const float* s = (i < 1024) ? bq : (i < 2048 ? bk : bv);
        bc[i] = s[i & 1023];
    }
}

// ------------- row softmax over 2048 cols, in place, bf16; 2 rows/block ----
__global__ __launch_bounds__(512) void k_softmax(__bf16* __restrict__ E) {
    const int tid = threadIdx.x;
    const int half = tid >> 8, t = tid & 255;
    __bf16* p = E + ((long long)blockIdx.x * 2 + half) * 2048;
    const int l = tid & 63, w4 = (tid >> 6) & 3;
    bf16x8 vb = *((const bf16x8*)p + t);
    float v[8];
#pragma unroll
    for (int i = 0; i < 8; ++i) v[i] = (float)vb[i];
    float m = v[0];
#pragma unroll
    for (int i = 1; i < 8; ++i) m = fmaxf(m, v[i]);
    for (int off = 32; off > 0; off >>= 1) m = fmaxf(m, __shfl_xor(m, off));
    __shared__ float redm[2][4], reds[2][4];
    if (l == 0) redm[half][w4] = m;
    __syncthreads();
    m = fmaxf(fmaxf(redm[half][0], redm[half][1]),
              fmaxf(redm[half][2], redm[half][3]));
    float e[8], s = 0.f;
#pragma unroll
    for (int i = 0; i < 8; ++i) { e[i] = __expf(v[i] - m); s += e[i]; }
    for (int off = 32; off > 0; off >>= 1) s += __shfl_xor(s, off);
    if (l == 0) reds[half][w4] = s;
    __syncthreads();
    s = reds[half][0] + reds[half][1] + reds[half][2] + reds[half][3];
    const float inv = 1.0f / s;
    bf16x8 o;
#pragma unroll
    for (int i = 0; i < 8; ++i) o[i] = (__bf16)(e[i] * inv);
    *((bf16x8*)p + t) = o;
}

// ------------- GEMM: C[z] = A[z] @ Bt[z]^T * scale (+bias) -------------
// 256x256 tile, BK=64, 8 waves (2x4), wave tile 128x64, 8-phase schedule,
// single barrier per phase + extra barrier fused with WV4 at P3/P7.
// LDS [row 256][64], chunk swizzle c' = c ^ (row&7) (c in 0..7 of 16B).
// MODE: 0 = bf16 C swapped, 1 = f32 C swapped, 2 = Q/K split swapped,
//       4 = V unswapped (cols -> Vt[b][h][s]).
template <int MODE, bool HAS_BIAS>
__global__ __launch_bounds__(512, 2) void gemm_bt(
    const __bf16* __restrict__ A, const __bf16* __restrict__ Bt,
    const float* __restrict__ bias, void* __restrict__ Cout,
    int K, int lda, int ldb, int ldc, int gy, int rpx, int bnc,
    float scale, long long sA, long long sB, long long sC) {
    constexpr bool SWP = (MODE != 4);
    __shared__ __align__(16) __bf16 Abuf0[16384];
    __shared__ __align__(16) __bf16 Bbuf0[16384];
    __shared__ __align__(16) __bf16 Abuf1[16384];
    __shared__ __align__(16) __bf16 Bbuf1[16384];

    // swizzled block mapping
    const int lid = blockIdx.x;
    const int xcd = lid & 7;
    const int jj = lid >> 3;
    const int bn = jj % bnc;
    const int rt = xcd * rpx + jj / bnc;
    const int z = rt / gy;
    const int bm = rt - z * gy;

    const __bf16* Ab = A + (long long)z * sA;
    const __bf16* Bb = Bt + (long long)z * sB;

    const int tid = threadIdx.x;
    const int l = tid & 63, w = tid >> 6;   // lane, wave 0..7
    const int wm = w >> 2, wn = w & 3;      // 2 x 4 wave grid

    // staging: thread t covers rows (t>>3)+64j, global chunk (t&7)^((t>>3)&7)
    const int rA = tid >> 3;
    const int cswz = (tid & 7) ^ (rA & 7);
    const __bf16* aSg = Ab + (long long)(bm * 256 + rA) * lda + cswz * 8;
    const __bf16* bSg = Bb + (long long)(bn * 256 + rA) * ldb + cswz * 8;
    const long long a64 = (long long)lda * 64;
    const long long b64 = (long long)ldb * 64;
    const int ldst = tid * 16;              // LDS byte base (linear)

    // ds-read fragment offsets (elements): row stride 64.
    // chunk for (kq4,kh): (kh*4+kq4) ^ (r16&7); kh=1 base = kh=0 base ^ 32.
    const int r16 = l & 15, kq4 = l >> 4;
    const int sw0 = kq4 ^ (r16 & 7);
    const int aro0 = (wm * 128 + r16) * 64 + sw0 * 8;
    const int aro1 = aro0 ^ 32;
    const int bro0 = (wn * 64 + r16) * 64 + sw0 * 8;
    const int bro1 = bro0 ^ 32;

    f32x4 acc[8][4] = {};
    bf16x8 bf[4][2];

#define ST_A(buf, j, t)                                                    \
    gl_lds16(aSg + (j) * a64 + (long long)(t) * 64,                        \
             (char*)(buf) + ldst + (j) * 8192)
#define ST_B(buf, j, t)                                                    \
    gl_lds16(bSg + (j) * b64 + (long long)(t) * 64,                        \
             (char*)(buf) + ldst + (j) * 8192)

#define RD_B(buf)                                                          \
    do {                                                                   \
        _Pragma("unroll") for (int ni = 0; ni < 4; ++ni) {                 \
            bf[ni][0] = *(const bf16x8*)((buf) + bro0 + ni * 1024);        \
            bf[ni][1] = *(const bf16x8*)((buf) + bro1 + ni * 1024);        \
        }                                                                  \
    } while (0)

#define BARR                                                               \
    do {                                                                   \
        __builtin_amdgcn_sched_barrier(0);                                 \
        __builtin_amdgcn_s_barrier();                                      \
        __builtin_amdgcn_sched_barrier(0);                                 \
    } while (0)
#define LGK0                                                               \
    do {                                                                   \
        asm volatile("s_waitcnt lgkmcnt(0)" ::: "memory");                 \
        __builtin_amdgcn_sched_barrier(0);                                 \
    } while (0)
#define WV4 asm volatile("s_waitcnt vmcnt(4)" ::: "memory")
#define WV0 asm volatile("s_waitcnt vmcnt(0)" ::: "memory")
#define NOW ((void)0)
#define TS4 do { WV4; BARR; } while (0)   // buffer-flip sync (P3/P7)
#define TS0 do { WV0; BARR; } while (0)   // tail drain

// Phase: [stages issue] [ds-reads issue] -> barrier -> lgkmcnt(0) ->
//        setprio(1)+16 MFMA -> TAILOP (NOW, or WV+BARR at P3/P7).
#define PHASE(Abuf, p, RB, RBUF, STAGES, TAILOP)                               \
    do {                                                                      \
        STAGES;                                                               \
        bf16x8 af0k0 = *(const bf16x8*)((Abuf) + aro0 + (2 * (p)) * 1024);     \
        bf16x8 af0k1 = *(const bf16x8*)((Abuf) + aro1 + (2 * (p)) * 1024);     \
        bf16x8 af1k0 = *(const bf16x8*)((Abuf) + aro0 + (2 * (p) + 1) * 1024); \
        bf16x8 af1k1 = *(const bf16x8*)((Abuf) + aro1 + (2 * (p) + 1) * 1024); \
        if (RB) RD_B(RBUF);                                                   \
        BARR;                                                                 \
        LGK0;                                                                 \
        __builtin_amdgcn_s_setprio(1);                                        \
        _Pragma("unroll") for (int ni = 0; ni < 4; ++ni) {                    \
            acc[2 * (p)][ni] = mfma16<SWP>(af0k0, bf[ni][0], acc[2*(p)][ni]); \
            acc[2 * (p)][ni] = mfma16<SWP>(af0k1, bf[ni][1], acc[2*(p)][ni]); \
            acc[2*(p)+1][ni] = mfma16<SWP>(af1k0, bf[ni][0], acc[2*(p)+1][ni]);\
            acc[2*(p)+1][ni] = mfma16<SWP>(af1k1, bf[ni][1], acc[2*(p)+1][ni]);\
        }                                                                     \
        __builtin_amdgcn_s_setprio(0);                                        \
        TAILOP;                                                               \
    } while (0)

    // Prologue: stage B(0), A(0), B(1); force B(0),A(0) (keep B(1) in flight).
    ST_B(Bbuf0, 0, 0); ST_B(Bbuf0, 1, 0); ST_B(Bbuf0, 2, 0); ST_B(Bbuf0, 3, 0);
    ST_A(Abuf0, 0, 0); ST_A(Abuf0, 1, 0); ST_A(Abuf0, 2, 0); ST_A(Abuf0, 3, 0);
    ST_B(Bbuf1, 0, 1); ST_B(Bbuf1, 1, 1); ST_B(Bbuf1, 2, 1); ST_B(Bbuf1, 3, 1);
    WV4;
    BARR;

    const int NT = K >> 6;  // K-tiles of 64; NT even, >= 4 for all dispatches
    // Stage ledger (rule: stage in phase p only if target-buffer reads ended
    // in phase <= p-2, or a TS-barrier intervenes): A(t+1)@P0, B(t+2)@P2+P3,
    // A(t+2)@P4+P5 (TS4@P3 intervenes after Abuf0 reads), B(t+3)@P6+P7.
    for (int t0 = 0; t0 + 3 < NT; t0 += 2) {
        PHASE(Abuf0, 0, 1, Bbuf0,
              (ST_A(Abuf1, 0, t0 + 1), ST_A(Abuf1, 1, t0 + 1),
               ST_A(Abuf1, 2, t0 + 1), ST_A(Abuf1, 3, t0 + 1)), NOW);
        PHASE(Abuf0, 1, 0, Bbuf0, NOW, NOW);
        PHASE(Abuf0, 2, 0, Bbuf0,
              (ST_B(Bbuf0, 0, t0 + 2), ST_B(Bbuf0, 1, t0 + 2)), NOW);
        PHASE(Abuf0, 3, 0, Bbuf0,
              (ST_B(Bbuf0, 2, t0 + 2), ST_B(Bbuf0, 3, t0 + 2)), TS4);
        PHASE(Abuf1, 0, 1, Bbuf1,
              (ST_A(Abuf0, 0, t0 + 2), ST_A(Abuf0, 1, t0 + 2)), NOW);
        PHASE(Abuf1, 1, 0, Bbuf1,
              (ST_A(Abuf0, 2, t0 + 2), ST_A(Abuf0, 3, t0 + 2)), NOW);
        PHASE(Abuf1, 2, 0, Bbuf1,
              (ST_B(Bbuf1, 0, t0 + 3), ST_B(Bbuf1, 1, t0 + 3)), NOW);
        PHASE(Abuf1, 3, 0, Bbuf1,
              (ST_B(Bbuf1, 2, t0 + 3), ST_B(Bbuf1, 3, t0 + 3)), TS4);
    }
    // Tail iteration (tiles NT-2, NT-1): stage only A(NT-1); drain at P3.
    {
        PHASE(Abuf0, 0, 1, Bbuf0,
              (ST_A(Abuf1, 0, NT - 1), ST_A(Abuf1, 1, NT - 1),
               ST_A(Abuf1, 2, NT - 1), ST_A(Abuf1, 3, NT - 1)), NOW);
        PHASE(Abuf0, 1, 0, Bbuf0, NOW, NOW);
        PHASE(Abuf0, 2, 0, Bbuf0, NOW, NOW);
        PHASE(Abuf0, 3, 0, Bbuf0, NOW, TS0);
        PHASE(Abuf1, 0, 1, Bbuf1, NOW, NOW);
        PHASE(Abuf1, 1, 0, Bbuf1, NOW, NOW);
        PHASE(Abuf1, 2, 0, Bbuf1, NOW, NOW);
        PHASE(Abuf1, 3, 0, Bbuf1, NOW, NOW);
    }
#undef ST_A
#undef ST_B
#undef RD_B
#undef BARR
#undef LGK0
#undef WV4
#undef WV0
#undef NOW
#undef TS4
#undef TS0
#undef PHASE

    const int quad = kq4;
    if constexpr (MODE == 2) {
        // swapped: row(s) = ...+r16, cols = ...+quad*4+rr -> bf16x4 stores
        __bf16* Qb = (__bf16*)Cout;
        const int part = bn >> 2;  // 0=Q 1=K
#pragma unroll
        for (int mi = 0; mi < 8; ++mi) {
            const int srow0 = bm * 256 + wm * 128 + mi * 16 + r16;
            const int b = srow0 >> 11;
            const int s0 = srow0 & 2047;
#pragma unroll
            for (int ni = 0; ni < 4; ++ni) {
                const int col0 = bn * 256 + wn * 64 + ni * 16 + quad * 4;
                const f32x4 bb = *(const f32x4*)(bias + col0);
                const int c1 = col0 - part * 1024;
                bf16x4 o;
#pragma unroll
                for (int rr = 0; rr < 4; ++rr) o[rr] = (__bf16)(acc[mi][ni][rr] + bb[rr]);
                *(bf16x4*)(Qb + (long long)part * 16777216 +
                           (long long)b * 2097152 + (long long)s0 * 1024 + c1) = o;
            }
        }
    } else if constexpr (MODE == 4) {
        // unswapped: col(h) = ...+r16, rows(s) = ...+quad*4+rr -> bf16x4 along s
        __bf16* Vb = (__bf16*)Cout;
#pragma unroll
        for (int mi = 0; mi < 8; ++mi) {
            const int srow0 = bm * 256 + wm * 128 + mi * 16 + quad * 4;
            const int b = srow0 >> 11;
            const int s0 = srow0 & 2047;
#pragma unroll
            for (int ni = 0; ni < 4; ++ni) {
                const int c1 = bn * 256 + wn * 64 + ni * 16 + r16;
                const float bb = HAS_BIAS ? bias[c1] : 0.0f;
                bf16x4 o;
#pragma unroll
                for (int rr = 0; rr < 4; ++rr) o[rr] = (__bf16)(acc[mi][ni][rr] + bb);
                *(bf16x4*)(Vb + (long long)b * 2097152 +
                           (long long)c1 * 2048 + s0) = o;
            }
        }
    } else {
        // MODE 0/1 swapped row-major: vector store of 4 consecutive cols
        const long long cbase = (long long)z * sC;
#pragma unroll
        for (int mi = 0; mi < 8; ++mi) {
            const int row = bm * 256 + wm * 128 + mi * 16 + r16;
#pragma unroll
            for (int ni = 0; ni < 4; ++ni) {
                const int col0 = bn * 256 + wn * 64 + ni * 16 + quad * 4;
                f32x4 v;
                if constexpr (HAS_BIAS) {
                    const f32x4 bb = *(const f32x4*)(bias + col0);
#pragma unroll
                    for (int rr = 0; rr < 4; ++rr) v[rr] = acc[mi][ni][rr] * scale + bb[rr];
                } else {
#pragma unroll
                    for (int rr = 0; rr < 4; ++rr) v[rr] = acc[mi][ni][rr] * scale;
                }
                if constexpr (MODE == 1) {
                    *(f32x4*)((float*)Cout + cbase + (long long)row * ldc + col0) = v;
                } else {
                    bf16x4 o;
#pragma unroll
                    for (int rr = 0; rr < 4; ++rr) o[rr] = (__bf16)v[rr];
                    *(bf16x4*)((__bf16*)Cout + cbase + (long long)row * ldc + col0) = o;
                }
            }
        }
    }
}

extern "C" void kernel_launch(void* const* d_in, const int* in_sizes, int n_in,
                              void* d_out, int out_size, void* d_ws, size_t ws_size,
                              hipStream_t stream) {
    const float* x  = (const float*)d_in[0];
    const float* wq = (const float*)d_in[1];
    const float* bq = (const float*)d_in[2];
    const float* wk = (const float*)d_in[3];
    const float* bk = (const float*)d_in[4];
    const float* wv = (const float*)d_in[5];
    const float* bv = (const float*)d_in[6];
    const float* wo = (const float*)d_in[7];
    const float* bo = (const float*)d_in[8];
    float* out = (float*)d_out;

    // ws layout (bf16 elems), ~200 MiB total.
    __bf16* ws  = (__bf16*)d_ws;
    __bf16* Xb  = ws;                   // 16,777,216 (phase 1; dead after QKV)
    __bf16* E   = ws;                   // 33,554,432 (phase 2, reuses Xb)
    __bf16* Q   = ws + 33554432;        // 16,777,216
    __bf16* Kb  = ws + 50331648;        // 16,777,216
    __bf16* Vt  = ws + 67108864;        // 16,777,216
    __bf16* Ctx = ws + 83886080;        // 16,777,216
    __bf16* WT  = ws + 100663296;       // 4,194,304
    float*  bc  = (float*)(ws + 104857600);  // 3072 fp32

    // prep: blocks [0,8192)=convert, [8192,9216)=W transposes, [9216,9228)=bcat
    k_prep<<<9228, 256, 0, stream>>>(x, wq, wk, wv, wo, bq, bk, bv, Xb, WT, bc);

    // Q,K: [16384,2048] = Xb @ WT[0:2048]^T + bcat -> Q, K (split epilogue)
    gemm_bt<2, true><<<512, 512, 0, stream>>>(
        Xb, WT, bc, Q, 1024, 1024, 1024, 0, 64, 8, 8, 1.0f, 0, 0, 0);

    // V: [16384,1024] = Xb @ WT[2048:3072]^T + bcat[2048:] -> Vt[b][h][s]
    gemm_bt<4, true><<<256, 512, 0, stream>>>(
        Xb, WT + 2097152, bc + 2048, Vt, 1024, 1024, 1024, 0, 64, 8, 4,
        1.0f, 0, 0, 0);

    // E[b] = Q[b] @ K[b]^T / 32
    gemm_bt<0, false><<<512, 512, 0, stream>>>(
        Q, Kb, nullptr, E, 1024, 1024, 1024, 2048, 8, 8, 8,
        0.03125f, 2097152, 2097152, 4194304);

    k_softmax<<<8192, 512, 0, stream>>>(E);

    // Ctx[b] = P[b] @ Vt[b]^T
    gemm_bt<0, false><<<256, 512, 0, stream>>>(
        E, Vt, nullptr, Ctx, 2048, 2048, 2048, 1024, 8, 8, 4,
        1.0f, 4194304, 2097152, 2097152);

    // out = Ctx @ Wo^T + bo (fp32)
    gemm_bt<1, true><<<256, 512, 0, stream>>>(
        Ctx, WT + 3145728, bo, out, 1024, 1024, 1024, 1024, 64, 8, 4,
        1.0f, 0, 0, 0);
}